// Round 3
// baseline (121.831 us; speedup 1.0000x reference)
//
#include <hip/hip_runtime.h>
#include <hip/hip_bf16.h>
#include <hip/hip_cooperative_groups.h>

namespace cg = cooperative_groups;

// Problem constants (B,N,H,O) = (2,512,128,32)
#define NN 512
#define HH 128
#define OO 32

// 2*log2(e): tanh(x) = 1 - 2/(2^(KL*xa)*2^(KL*xb)+1) with x = xa+xb
#define KL 2.8853900817779268f

__device__ __forceinline__ float vexp2(float x) {
    float r; asm("v_exp_f32 %0, %1" : "=v"(r) : "v"(x)); return r;
}
__device__ __forceinline__ float vrcp(float x) {
    float r; asm("v_rcp_f32 %0, %1" : "=v"(r) : "v"(x)); return r;
}
__device__ __forceinline__ float tanh_fast(float x) {
    float e = vexp2(KL * x);
    return 1.0f - 2.0f * vrcp(e + 1.0f);
}
__device__ __forceinline__ float waveRedMax(float v) {
#pragma unroll
    for (int off = 32; off > 0; off >>= 1) v = fmaxf(v, __shfl_xor(v, off, 64));
    return v;
}
__device__ __forceinline__ float waveRedSum(float v) {
#pragma unroll
    for (int off = 32; off > 0; off >>= 1) v += __shfl_xor(v, off, 64);
    return v;
}

// ---------------------------------------------------------------------------
// Single cooperative kernel. 256 blocks x 1024 threads (1 block/CU).
// Phase 0: weight transposes (gather, tiny)
// Phase 1: per-block prep of its own 4 rows: q,Ezi -> LDS; Ezj,kT -> global
// grid.sync
// Phase 2: scores (kT read once, h-split) -> softmax -> tanh-core -> tail GEMVs
// ---------------------------------------------------------------------------
__global__ __launch_bounds__(1024, 4) void ode_mega(
    const float* __restrict__ z, const float* __restrict__ s_t,
    const float* __restrict__ W1, const float* __restrict__ b1,
    const float* __restrict__ W2, const float* __restrict__ b2,
    const float* __restrict__ Wq, const float* __restrict__ bq,
    const float* __restrict__ Wk, const float* __restrict__ bk,
    const float* __restrict__ W3, const float* __restrict__ b3,
    const float* __restrict__ W4, const float* __restrict__ b4,
    float* __restrict__ out,
    float* __restrict__ kTG, float* __restrict__ EzjG,
    float* __restrict__ WqT, float* __restrict__ W1iT, float* __restrict__ W1jT,
    float* __restrict__ WkT, float* __restrict__ W2T, float* __restrict__ W3T,
    float* __restrict__ W4T) {

    __shared__ float zrow[4][HH];        // 2KB  (reused as agg in tail)
    __shared__ float srow[4][OO];        // 0.5KB
    __shared__ float q4T[HH][4];         // 2KB  q packed [h][r]
    __shared__ float c4T[HH][4];         // 2KB  Ezi packed [h][r]
    __shared__ float attnT[NN][4];       // 8KB  attn packed [j][r]
    __shared__ float scp[2][4][NN];      // 16KB score partials
    __shared__ float part[16][4][HH];    // 32KB D partials / prep partials / tail partials
    __shared__ float UL[4][HH];          // 2KB
    __shared__ float h1L[4][HH];         // 2KB
    __shared__ float redA[16], redB[16];

    cg::grid_group grid = cg::this_grid();
    int t = threadIdx.x;
    int r0 = blockIdx.x * 4;             // global row base (b*512 + i0)
    int b = blockIdx.x >> 7;
    int i0 = (blockIdx.x & 127) * 4;

    // ---- Phase 0: weight transposes ----
    {
        int tid = blockIdx.x * 1024 + t;
        if (tid < 16384) WqT[tid] = Wq[(tid & 127) * 128 + (tid >> 7)];
        else if ((tid -= 16384) < 16384) W1iT[tid] = W1[(tid & 127) * 256 + (tid >> 7)];
        else if ((tid -= 16384) < 16384) W1jT[tid] = W1[(tid & 127) * 256 + 128 + (tid >> 7)];
        else if ((tid -= 16384) < 4096)  WkT[tid] = Wk[(tid & 127) * 32 + (tid >> 7)];
        else if ((tid -= 4096) < 16384)  W2T[tid] = W2[(tid & 127) * 128 + (tid >> 7)];
        else if ((tid -= 16384) < 16384) W3T[tid] = W3[(tid & 127) * 128 + (tid >> 7)];
        else if ((tid -= 16384) < 16384) W4T[tid] = W4[(tid & 127) * 128 + (tid >> 7)];
    }

    // ---- Phase 1 stage A: load this block's z/s_t rows ----
    if (t < 4 * HH) zrow[t >> 7][t & 127] = z[(size_t)r0 * HH + t];
    if (t < 4 * OO) srow[t >> 5][t & 31] = s_t[(size_t)r0 * OO + t];
    grid.sync();   // weights transposed + zrow/srow loaded (includes block sync)

    // ---- Phase 1 stage B: prep GEMVs, (kq, rowpair) split ----
    {
        // pp2[kq][rp][ro][X][h], X: 0=q,1=zi,2=zj,3=k
        float (*pp2)[2][2][4][HH] = reinterpret_cast<float (*)[2][2][4][HH]>(part);
        int h = t & 127;
        int g = t >> 7;           // 0..7
        int kq = g & 3;           // k-quarter
        int rp = g >> 2;          // row-pair
        int ra = rp * 2, rb = ra + 1;
        float aq0 = 0, aq1 = 0, ai0 = 0, ai1 = 0, aj0 = 0, aj1 = 0;
        int k0 = kq * 32;
#pragma unroll 8
        for (int k = k0; k < k0 + 32; k++) {
            float wq = WqT[k * HH + h], wi = W1iT[k * HH + h], wj = W1jT[k * HH + h];
            float z0 = zrow[ra][k], z1 = zrow[rb][k];
            aq0 = fmaf(z0, wq, aq0); aq1 = fmaf(z1, wq, aq1);
            ai0 = fmaf(z0, wi, ai0); ai1 = fmaf(z1, wi, ai1);
            aj0 = fmaf(z0, wj, aj0); aj1 = fmaf(z1, wj, aj1);
        }
        float ak0 = 0, ak1 = 0;
        int o0 = kq * 8;
#pragma unroll
        for (int o = o0; o < o0 + 8; o++) {
            float wk = WkT[o * HH + h];
            ak0 = fmaf(srow[ra][o], wk, ak0); ak1 = fmaf(srow[rb][o], wk, ak1);
        }
        pp2[kq][rp][0][0][h] = aq0; pp2[kq][rp][1][0][h] = aq1;
        pp2[kq][rp][0][1][h] = ai0; pp2[kq][rp][1][1][h] = ai1;
        pp2[kq][rp][0][2][h] = aj0; pp2[kq][rp][1][2][h] = aj1;
        pp2[kq][rp][0][3][h] = ak0; pp2[kq][rp][1][3][h] = ak1;
    }
    __syncthreads();
    if (t < 512) {
        float (*pp2)[2][2][4][HH] = reinterpret_cast<float (*)[2][2][4][HH]>(part);
        int h = t & 127, r = t >> 7, rp = r >> 1, ro = r & 1;
        float aq = 0, ai = 0, aj = 0, ak = 0;
#pragma unroll
        for (int kq = 0; kq < 4; kq++) {
            aq += pp2[kq][rp][ro][0][h]; ai += pp2[kq][rp][ro][1][h];
            aj += pp2[kq][rp][ro][2][h]; ak += pp2[kq][rp][ro][3][h];
        }
        int gr = r0 + r;
        q4T[h][r] = aq + bq[h];
        c4T[h][r] = vexp2(KL * (ai + b1[h]));
        EzjG[(size_t)gr * HH + h] = vexp2(KL * aj);
        int bb = gr >> 9, jj = gr & 511;
        kTG[((size_t)bb * HH + h) * NN + jj] = ak + bk[h];
    }
    grid.sync();   // EzjG/kTG globally visible

    // ---- Phase 2a: scores — kT read ONCE per block (h-split) ----
    {
        int hs = t >> 9, j = t & 511, h0 = hs * 64;
        const float* kb = kTG + ((size_t)b * HH + h0) * NN + j;
        float s0 = 0, s1 = 0, s2 = 0, s3 = 0;
#pragma unroll 8
        for (int hh = 0; hh < 64; hh++) {
            float kv = kb[(size_t)hh * NN];
            float4 qv = *(const float4*)q4T[h0 + hh];   // broadcast
            s0 = fmaf(qv.x, kv, s0); s1 = fmaf(qv.y, kv, s1);
            s2 = fmaf(qv.z, kv, s2); s3 = fmaf(qv.w, kv, s3);
        }
        scp[hs][0][j] = s0; scp[hs][1][j] = s1;
        scp[hs][2][j] = s2; scp[hs][3][j] = s3;
    }
    __syncthreads();

    // ---- Phase 2b: masked softmax (2 rows per thread-half) ----
    {
        int rp = t >> 9, j = t & 511;
        int lr0 = rp * 2, lr1 = lr0 + 1;
        const float sc = 0.08838834764831845f;  // 1/sqrt(128)
        float s0 = (scp[0][lr0][j] + scp[1][lr0][j]) * sc;
        float s1 = (scp[0][lr1][j] + scp[1][lr1][j]) * sc;
        if (j == i0 + lr0) s0 = -1e30f;
        if (j == i0 + lr1) s1 = -1e30f;
        int lane = t & 63, w = t >> 6, wb = rp * 8;
        float m0 = waveRedMax(s0), m1 = waveRedMax(s1);
        if (lane == 0) { redA[w] = m0; redB[w] = m1; }
        __syncthreads();
        float mm0 = redA[wb], mm1 = redB[wb];
#pragma unroll
        for (int k = 1; k < 8; k++) { mm0 = fmaxf(mm0, redA[wb + k]); mm1 = fmaxf(mm1, redB[wb + k]); }
        float e0 = __expf(s0 - mm0), e1 = __expf(s1 - mm1);
        float p0 = waveRedSum(e0), p1 = waveRedSum(e1);
        __syncthreads();
        if (lane == 0) { redA[w] = p0; redB[w] = p1; }
        __syncthreads();
        float S0 = redA[wb], S1 = redB[wb];
#pragma unroll
        for (int k = 1; k < 8; k++) { S0 += redA[wb + k]; S1 += redB[wb + k]; }
        attnT[j][lr0] = e0 * __fdividef(1.0f, S0);
        attnT[j][lr1] = e1 * __fdividef(1.0f, S1);
    }
    __syncthreads();

    // ---- Phase 2c: tanh core. thread = (j-slice qs, h-pair). float2 coalesced ----
    {
        int lane6 = t & 63, qs = t >> 6;          // 16 slices x 32 j
        int hp = lane6 * 2;
        int jb = qs * 32;
        float4 cA = *(const float4*)c4T[hp];       // Ezi rows 0..3 at h=hp
        float4 cB = *(const float4*)c4T[hp + 1];   // at h=hp+1
        const float2* zb2 = (const float2*)EzjG + (size_t)b * NN * 64 + lane6;
        float a0A = 0, a1A = 0, a2A = 0, a3A = 0;
        float a0B = 0, a1B = 0, a2B = 0, a3B = 0;
#pragma unroll 8
        for (int jj = 0; jj < 32; jj++) {
            int j = jb + jj;
            float2 E = zb2[(size_t)j * 64];
            float4 w = *(const float4*)attnT[j];   // broadcast
            a0A = fmaf(w.x, vrcp(fmaf(cA.x, E.x, 1.0f)), a0A);
            a1A = fmaf(w.y, vrcp(fmaf(cA.y, E.x, 1.0f)), a1A);
            a2A = fmaf(w.z, vrcp(fmaf(cA.z, E.x, 1.0f)), a2A);
            a3A = fmaf(w.w, vrcp(fmaf(cA.w, E.x, 1.0f)), a3A);
            a0B = fmaf(w.x, vrcp(fmaf(cB.x, E.y, 1.0f)), a0B);
            a1B = fmaf(w.y, vrcp(fmaf(cB.y, E.y, 1.0f)), a1B);
            a2B = fmaf(w.z, vrcp(fmaf(cB.z, E.y, 1.0f)), a2B);
            a3B = fmaf(w.w, vrcp(fmaf(cB.w, E.y, 1.0f)), a3B);
        }
        *(float2*)&part[qs][0][hp] = make_float2(a0A, a0B);
        *(float2*)&part[qs][1][hp] = make_float2(a1A, a1B);
        *(float2*)&part[qs][2][hp] = make_float2(a2A, a2B);
        *(float2*)&part[qs][3][hp] = make_float2(a3A, a3B);
    }
    __syncthreads();
    if (t < 512) {
        int rr = t >> 7, hh = t & 127;
        float s = 0;
#pragma unroll
        for (int q = 0; q < 16; q++) s += part[q][rr][hh];
        UL[rr][hh] = fmaf(-2.0f, s, 1.0f);   // U = 1 - 2*sum (softmax sums to 1)
    }
    __syncthreads();

    // ---- Phase 2d: tail GEMVs (k split in halves) ----
    int r = (t >> 7) & 3, ks = t >> 9, h = t & 127, k0 = ks * 64;
    {
        float acc = 0;
#pragma unroll 4
        for (int k = 0; k < 64; k++) acc = fmaf(UL[r][k0 + k], W2T[(k0 + k) * HH + h], acc);
        part[ks][r][h] = acc;
    }
    __syncthreads();
    if (t < 512) {
        int rr = t >> 7, hh = t & 127;
        zrow[rr][hh] = part[0][rr][hh] + part[1][rr][hh] + b2[hh];
    }
    __syncthreads();
    {
        float acc = 0;
#pragma unroll 4
        for (int k = 0; k < 64; k++) acc = fmaf(zrow[r][k0 + k], W3T[(k0 + k) * HH + h], acc);
        part[ks][r][h] = acc;
    }
    __syncthreads();
    if (t < 512) {
        int rr = t >> 7, hh = t & 127;
        h1L[rr][hh] = tanh_fast(part[0][rr][hh] + part[1][rr][hh] + b3[hh]);
    }
    __syncthreads();
    {
        float acc = 0;
#pragma unroll 4
        for (int k = 0; k < 64; k++) acc = fmaf(h1L[r][k0 + k], W4T[(k0 + k) * HH + h], acc);
        part[ks][r][h] = acc;
    }
    __syncthreads();
    if (t < 512) {
        int rr = t >> 7, hh = t & 127;
        out[(size_t)(r0 + rr) * HH + hh] = part[0][rr][hh] + part[1][rr][hh] + b4[hh];
    }
}

extern "C" void kernel_launch(void* const* d_in, const int* in_sizes, int n_in,
                              void* d_out, int out_size, void* d_ws, size_t ws_size,
                              hipStream_t stream) {
    const float* z   = (const float*)d_in[0];
    const float* s_t = (const float*)d_in[1];
    const float* W1  = (const float*)d_in[2];
    const float* b1  = (const float*)d_in[3];
    const float* W2  = (const float*)d_in[4];
    const float* b2  = (const float*)d_in[5];
    const float* Wq  = (const float*)d_in[6];
    const float* bq  = (const float*)d_in[7];
    const float* Wk  = (const float*)d_in[8];
    const float* bk  = (const float*)d_in[9];
    const float* W3  = (const float*)d_in[10];
    const float* b3  = (const float*)d_in[11];
    const float* W4  = (const float*)d_in[12];
    const float* b4  = (const float*)d_in[13];
    float* out = (float*)d_out;

    float* ws   = (float*)d_ws;
    float* kT   = ws;                 // 131072  ([b][h][j])
    float* Ezj  = ws + 131072;        // 131072  ([b][j][h])
    float* WqT  = ws + 262144;        // 16384
    float* W1iT = WqT + 16384;
    float* W1jT = W1iT + 16384;
    float* WkT  = W1jT + 16384;       // 4096
    float* W2T  = WkT + 4096;
    float* W3T  = W2T + 16384;
    float* W4T  = W3T + 16384;

    void* args[] = {
        (void*)&z, (void*)&s_t, (void*)&W1, (void*)&b1, (void*)&W2, (void*)&b2,
        (void*)&Wq, (void*)&bq, (void*)&Wk, (void*)&bk, (void*)&W3, (void*)&b3,
        (void*)&W4, (void*)&b4, (void*)&out, (void*)&kT, (void*)&Ezj,
        (void*)&WqT, (void*)&W1iT, (void*)&W1jT, (void*)&WkT,
        (void*)&W2T, (void*)&W3T, (void*)&W4T
    };
    hipLaunchCooperativeKernel((void*)ode_mega, dim3(256), dim3(1024), args, 0, stream);
}

// Round 4
// 40.820 us; speedup vs baseline: 2.9846x; 2.9846x over previous
//
#include <hip/hip_runtime.h>
#include <hip/hip_bf16.h>

// Problem constants (B,N,H,O) = (2,512,128,32)
#define NN 512
#define HH 128
#define OO 32

// 2*log2(e): tanh(x) = 1 - 2/(2^(KL*xa)*2^(KL*xb)+1) with x = xa+xb
#define KL 2.8853900817779268f

__device__ __forceinline__ float vexp2(float x) {
    float r; asm("v_exp_f32 %0, %1" : "=v"(r) : "v"(x)); return r;
}
__device__ __forceinline__ float vrcp(float x) {
    float r; asm("v_rcp_f32 %0, %1" : "=v"(r) : "v"(x)); return r;
}
__device__ __forceinline__ float tanh_fast(float x) {
    float e = vexp2(KL * x);
    return 1.0f - 2.0f * vrcp(e + 1.0f);
}
__device__ __forceinline__ float waveRedMax(float v) {
#pragma unroll
    for (int off = 32; off > 0; off >>= 1) v = fmaxf(v, __shfl_xor(v, off, 64));
    return v;
}
__device__ __forceinline__ float waveRedSum(float v) {
#pragma unroll
    for (int off = 32; off > 0; off >>= 1) v += __shfl_xor(v, off, 64);
    return v;
}
__device__ __forceinline__ float red8(float v) {   // sum within 8-lane group
    v += __shfl_xor(v, 1, 64); v += __shfl_xor(v, 2, 64); v += __shfl_xor(v, 4, 64);
    return v;
}
__device__ __forceinline__ float dot16(const float4* w, const float* x) {
    float a = 0;
#pragma unroll
    for (int i = 0; i < 4; i++) {
        float4 xv = *(const float4*)(x + i * 4);
        a = fmaf(xv.x, w[i].x, a); a = fmaf(xv.y, w[i].y, a);
        a = fmaf(xv.z, w[i].z, a); a = fmaf(xv.w, w[i].w, a);
    }
    return a;
}

// ---------------------------------------------------------------------------
// K1: prep — 512 blocks x 1024 thr, 2 rows/block. Original-layout weights,
// coalesced float4 reads, 8-lane shuffle reduce. No transpose kernel.
//   q = z@Wq.T+bq ; Ezi = 2^(KL*(z@W1i.T+b1)) ; Ezj = 2^(KL*z@W1j.T) ;
//   kT[b][h][j] = (s_t@Wk.T+bk) transposed.
// ---------------------------------------------------------------------------
__global__ __launch_bounds__(1024, 8) void prep_kernel(
    const float* __restrict__ z, const float* __restrict__ s_t,
    const float* __restrict__ W1, const float* __restrict__ b1,
    const float* __restrict__ Wq, const float* __restrict__ bq,
    const float* __restrict__ Wk, const float* __restrict__ bk,
    float* __restrict__ qG, float* __restrict__ EziG,
    float* __restrict__ EzjG, float* __restrict__ kTG) {
    __shared__ float zrow[2][HH];
    __shared__ float srow[2][OO];
    int t = threadIdx.x;
    int r0 = blockIdx.x * 2;
    if (t < 2 * HH) zrow[t >> 7][t & 127] = z[(size_t)r0 * HH + t];
    else if (t < 2 * HH + 2 * OO) {
        int u = t - 2 * HH;
        srow[u >> 5][u & 31] = s_t[(size_t)r0 * OO + u];
    }
    __syncthreads();

    int kq = t & 7, h = t >> 3;      // 8 lanes per output row h
    float vbq = bq[h], vb1 = b1[h], vbk = bk[h];
    float4 w[4];

    // ---- Wq ----
    {
        const float4* Wp = (const float4*)(Wq + (size_t)h * HH) + kq * 4;
#pragma unroll
        for (int i = 0; i < 4; i++) w[i] = Wp[i];
        float a0 = dot16(w, &zrow[0][kq * 16]);
        float a1 = dot16(w, &zrow[1][kq * 16]);
        a0 = red8(a0); a1 = red8(a1);
        if (kq == 0) {
            qG[(size_t)r0 * HH + h] = a0 + vbq;
            qG[(size_t)(r0 + 1) * HH + h] = a1 + vbq;
        }
    }
    // ---- W1i ----
    {
        const float4* Wp = (const float4*)(W1 + (size_t)h * 2 * HH) + kq * 4;
#pragma unroll
        for (int i = 0; i < 4; i++) w[i] = Wp[i];
        float a0 = dot16(w, &zrow[0][kq * 16]);
        float a1 = dot16(w, &zrow[1][kq * 16]);
        a0 = red8(a0); a1 = red8(a1);
        if (kq == 0) {
            EziG[(size_t)r0 * HH + h] = vexp2(KL * (a0 + vb1));
            EziG[(size_t)(r0 + 1) * HH + h] = vexp2(KL * (a1 + vb1));
        }
    }
    // ---- W1j ----
    {
        const float4* Wp = (const float4*)(W1 + (size_t)h * 2 * HH + HH) + kq * 4;
#pragma unroll
        for (int i = 0; i < 4; i++) w[i] = Wp[i];
        float a0 = dot16(w, &zrow[0][kq * 16]);
        float a1 = dot16(w, &zrow[1][kq * 16]);
        a0 = red8(a0); a1 = red8(a1);
        if (kq == 0) {
            EzjG[(size_t)r0 * HH + h] = vexp2(KL * a0);
            EzjG[(size_t)(r0 + 1) * HH + h] = vexp2(KL * a1);
        }
    }
    // ---- Wk (128x32): 4 o-values per lane ----
    {
        float4 wk = ((const float4*)(Wk + (size_t)h * OO))[kq];
        float4 s0 = *(const float4*)&srow[0][kq * 4];
        float4 s1 = *(const float4*)&srow[1][kq * 4];
        float a0 = s0.x * wk.x + s0.y * wk.y + s0.z * wk.z + s0.w * wk.w;
        float a1 = s1.x * wk.x + s1.y * wk.y + s1.z * wk.z + s1.w * wk.w;
        a0 = red8(a0); a1 = red8(a1);
        if (kq == 0) {
            int b0 = r0 >> 9, j0 = r0 & 511;
            kTG[((size_t)b0 * HH + h) * NN + j0] = a0 + vbk;
            int b1_ = (r0 + 1) >> 9, j1 = (r0 + 1) & 511;
            kTG[((size_t)b1_ * HH + h) * NN + j1] = a1 + vbk;
        }
    }
}

// ---------------------------------------------------------------------------
// K2: fused — 512 blocks x 1024 thr, 2 attention rows per block.
//   A: load q/Ezi packed [h][2]
//   B: scores, kT read once (h-split), LDS-broadcast q
//   C: masked softmax
//   D: acc += attn * rcp(fma(Ezi,Ezj,1)); U = 1-2*acc
//   E: tail GEMVs from ORIGINAL W2/W3/W4 layout (8-lane split + shuffle reduce)
// ---------------------------------------------------------------------------
__global__ __launch_bounds__(1024, 8) void fused_kernel(
    const float* __restrict__ qG, const float* __restrict__ kTG,
    const float* __restrict__ EziG, const float* __restrict__ EzjG,
    const float* __restrict__ W2, const float* __restrict__ b2,
    const float* __restrict__ W3, const float* __restrict__ b3,
    const float* __restrict__ W4, const float* __restrict__ b4,
    float* __restrict__ out) {
    __shared__ float q2T[HH][2];         // 1KB  q packed [h][r]
    __shared__ float c2T[HH][2];         // 1KB  Ezi packed [h][r]
    __shared__ float attnT[NN][2];       // 4KB  attn packed [j][r]
    __shared__ float scp[2][2][NN];      // 8KB  score partials [hs][r][j]
    __shared__ float part[16][2][HH];    // 16KB D partials [jslice][r][h]
    __shared__ float UL[2][HH];          // 1KB
    __shared__ float aggL[2][HH];        // 1KB
    __shared__ float h1L[2][HH];         // 1KB
    __shared__ float redA[16], redB[16];

    int t = threadIdx.x;
    int bid = blockIdx.x;
    int b = bid >> 8;
    int i0 = (bid & 255) * 2;
    int r0 = bid * 2;                    // global row base

    // ---- A ----
    if (t < 256)      { int h = t >> 1, r = t & 1; q2T[h][r] = qG[(size_t)(r0 + r) * HH + h]; }
    else if (t < 512) { int u = t - 256, h = u >> 1, r = u & 1; c2T[h][r] = EziG[(size_t)(r0 + r) * HH + h]; }
    __syncthreads();

    // ---- B: scores ----
    {
        int j = t & 511, hs = t >> 9, h0 = hs * 64;
        const float* kb = kTG + ((size_t)b * HH + h0) * NN + j;
        float s0 = 0, s1 = 0;
#pragma unroll 8
        for (int hh = 0; hh < 64; hh++) {
            float kv = kb[(size_t)hh * NN];
            float2 qv = *(const float2*)q2T[h0 + hh];   // broadcast
            s0 = fmaf(qv.x, kv, s0); s1 = fmaf(qv.y, kv, s1);
        }
        scp[hs][0][j] = s0; scp[hs][1][j] = s1;
    }
    __syncthreads();

    // ---- C: softmax (1 row per thread-half) ----
    {
        int r = t >> 9, j = t & 511;
        const float sc = 0.08838834764831845f;  // 1/sqrt(128)
        float s = (scp[0][r][j] + scp[1][r][j]) * sc;
        if (j == i0 + r) s = -1e30f;
        int lane = t & 63, w = t >> 6, wb = r * 8;
        float m = waveRedMax(s);
        if (lane == 0) redA[w] = m;
        __syncthreads();
        float mm = redA[wb];
#pragma unroll
        for (int k = 1; k < 8; k++) mm = fmaxf(mm, redA[wb + k]);
        float e = __expf(s - mm);
        float p = waveRedSum(e);
        if (lane == 0) redB[w] = p;
        __syncthreads();
        float S = redB[wb];
#pragma unroll
        for (int k = 1; k < 8; k++) S += redB[wb + k];
        attnT[j][r] = e * __fdividef(1.0f, S);
    }
    __syncthreads();

    // ---- D: rcp core. thread = (j-slice, h-pair); float2 coalesced Ezj ----
    {
        int lane6 = t & 63, qs = t >> 6;
        int hp = lane6 * 2;
        float2 cA = *(const float2*)c2T[hp];
        float2 cB = *(const float2*)c2T[hp + 1];
        const float2* zb2 = (const float2*)(EzjG + (size_t)b * NN * HH) + lane6;
        float a0A = 0, a1A = 0, a0B = 0, a1B = 0;
        int jb = qs * 32;
#pragma unroll 8
        for (int jj = 0; jj < 32; jj++) {
            int j = jb + jj;
            float2 E = zb2[(size_t)j * 64];
            float2 w = *(const float2*)attnT[j];        // broadcast
            a0A = fmaf(w.x, vrcp(fmaf(cA.x, E.x, 1.0f)), a0A);
            a1A = fmaf(w.y, vrcp(fmaf(cA.y, E.x, 1.0f)), a1A);
            a0B = fmaf(w.x, vrcp(fmaf(cB.x, E.y, 1.0f)), a0B);
            a1B = fmaf(w.y, vrcp(fmaf(cB.y, E.y, 1.0f)), a1B);
        }
        *(float2*)&part[qs][0][hp] = make_float2(a0A, a0B);
        *(float2*)&part[qs][1][hp] = make_float2(a1A, a1B);
    }
    __syncthreads();
    if (t < 256) {
        int r = t >> 7, h = t & 127;
        float s = 0;
#pragma unroll
        for (int q = 0; q < 16; q++) s += part[q][r][h];
        UL[r][h] = fmaf(-2.0f, s, 1.0f);   // U = 1 - 2*sum (softmax sums to 1)
    }
    __syncthreads();

    // ---- E: tail GEMVs, original weight layout, 8-lane split ----
    {
        int kq = t & 7, h = t >> 3;
        float vb2 = b2[h], vb3 = b3[h], vb4 = b4[h];
        float4 w[4];
        // agg = U@W2.T + b2
        {
            const float4* Wp = (const float4*)(W2 + (size_t)h * HH) + kq * 4;
#pragma unroll
            for (int i = 0; i < 4; i++) w[i] = Wp[i];
            float a0 = dot16(w, &UL[0][kq * 16]);
            float a1 = dot16(w, &UL[1][kq * 16]);
            a0 = red8(a0); a1 = red8(a1);
            if (kq == 0) { aggL[0][h] = a0 + vb2; aggL[1][h] = a1 + vb2; }
        }
        __syncthreads();
        // h1 = tanh(agg@W3.T + b3)
        {
            const float4* Wp = (const float4*)(W3 + (size_t)h * HH) + kq * 4;
#pragma unroll
            for (int i = 0; i < 4; i++) w[i] = Wp[i];
            float a0 = dot16(w, &aggL[0][kq * 16]);
            float a1 = dot16(w, &aggL[1][kq * 16]);
            a0 = red8(a0); a1 = red8(a1);
            if (kq == 0) { h1L[0][h] = tanh_fast(a0 + vb3); h1L[1][h] = tanh_fast(a1 + vb3); }
        }
        __syncthreads();
        // out = h1@W4.T + b4
        {
            const float4* Wp = (const float4*)(W4 + (size_t)h * HH) + kq * 4;
#pragma unroll
            for (int i = 0; i < 4; i++) w[i] = Wp[i];
            float a0 = dot16(w, &h1L[0][kq * 16]);
            float a1 = dot16(w, &h1L[1][kq * 16]);
            a0 = red8(a0); a1 = red8(a1);
            if (kq == 0) {
                out[(size_t)r0 * HH + h] = a0 + vb4;
                out[(size_t)(r0 + 1) * HH + h] = a1 + vb4;
            }
        }
    }
}

extern "C" void kernel_launch(void* const* d_in, const int* in_sizes, int n_in,
                              void* d_out, int out_size, void* d_ws, size_t ws_size,
                              hipStream_t stream) {
    const float* z   = (const float*)d_in[0];
    const float* s_t = (const float*)d_in[1];
    const float* W1  = (const float*)d_in[2];
    const float* b1  = (const float*)d_in[3];
    const float* W2  = (const float*)d_in[4];
    const float* b2  = (const float*)d_in[5];
    const float* Wq  = (const float*)d_in[6];
    const float* bq  = (const float*)d_in[7];
    const float* Wk  = (const float*)d_in[8];
    const float* bk  = (const float*)d_in[9];
    const float* W3  = (const float*)d_in[10];
    const float* b3  = (const float*)d_in[11];
    const float* W4  = (const float*)d_in[12];
    const float* b4  = (const float*)d_in[13];
    float* out = (float*)d_out;

    float* ws  = (float*)d_ws;
    float* qG  = ws;                 // 131072
    float* kT  = ws + 131072;        // 131072  ([b][h][j])
    float* Ezi = ws + 262144;        // 131072
    float* Ezj = ws + 393216;        // 131072

    hipLaunchKernelGGL(prep_kernel, dim3(512), dim3(1024), 0, stream,
                       z, s_t, W1, b1, Wq, bq, Wk, bk, qG, Ezi, Ezj, kT);
    hipLaunchKernelGGL(fused_kernel, dim3(512), dim3(1024), 0, stream,
                       qG, kT, Ezi, Ezj, W2, b2, W3, b3, W4, b4, out);
}

// Round 5
// 32.977 us; speedup vs baseline: 3.6944x; 1.2378x over previous
//
#include <hip/hip_runtime.h>
#include <hip/hip_bf16.h>

// Problem constants (B,N,H,O) = (2,512,128,32)
#define NN 512
#define HH 128
#define OO 32

// 2*log2(e): tanh(x) = 1 - 2/(2^(KL*xa)*2^(KL*xb)+1) with x = xa+xb
#define KL 2.8853900817779268f

__device__ __forceinline__ float vexp2(float x) {
    float r; asm("v_exp_f32 %0, %1" : "=v"(r) : "v"(x)); return r;
}
__device__ __forceinline__ float vrcp(float x) {
    float r; asm("v_rcp_f32 %0, %1" : "=v"(r) : "v"(x)); return r;
}
__device__ __forceinline__ float tanh_fast(float x) {
    float e = vexp2(KL * x);
    return 1.0f - 2.0f * vrcp(e + 1.0f);
}
__device__ __forceinline__ float waveRedMax(float v) {
#pragma unroll
    for (int off = 32; off > 0; off >>= 1) v = fmaxf(v, __shfl_xor(v, off, 64));
    return v;
}
__device__ __forceinline__ float waveRedSum(float v) {
#pragma unroll
    for (int off = 32; off > 0; off >>= 1) v += __shfl_xor(v, off, 64);
    return v;
}
__device__ __forceinline__ float red8(float v) {   // sum within 8-lane group
    v += __shfl_xor(v, 1, 64); v += __shfl_xor(v, 2, 64); v += __shfl_xor(v, 4, 64);
    return v;
}
__device__ __forceinline__ float dot16(const float4* w, const float* x) {
    float a = 0;
#pragma unroll
    for (int i = 0; i < 4; i++) {
        float4 xv = *(const float4*)(x + i * 4);
        a = fmaf(xv.x, w[i].x, a); a = fmaf(xv.y, w[i].y, a);
        a = fmaf(xv.z, w[i].z, a); a = fmaf(xv.w, w[i].w, a);
    }
    return a;
}

// ---------------------------------------------------------------------------
// K1: prep — 256 blocks x 1024 thr, 4 rows/block (halves weight re-reads).
// Original-layout weights, coalesced float4 reads, 8-lane shuffle reduce.
//   qP/cP packed [rowgroup][h][4] for fused's coalesced load.
//   Ezj[gr][h] row-major ; kT[b][h][j] transposed.
// ---------------------------------------------------------------------------
__global__ __launch_bounds__(1024, 4) void prep_kernel(
    const float* __restrict__ z, const float* __restrict__ s_t,
    const float* __restrict__ W1, const float* __restrict__ b1,
    const float* __restrict__ Wq, const float* __restrict__ bq,
    const float* __restrict__ Wk, const float* __restrict__ bk,
    float* __restrict__ qP, float* __restrict__ cP,
    float* __restrict__ EzjG, float* __restrict__ kTG) {
    __shared__ float zrow[4][HH];
    __shared__ float srow[4][OO];
    int t = threadIdx.x;
    int bid = blockIdx.x;
    int r0 = bid * 4;
    if (t < 4 * HH) zrow[t >> 7][t & 127] = z[(size_t)r0 * HH + t];
    else if (t < 4 * HH + 4 * OO) {
        int u = t - 4 * HH;
        srow[u >> 5][u & 31] = s_t[(size_t)r0 * OO + u];
    }
    __syncthreads();

    int kq = t & 7, h = t >> 3;      // 8 lanes per output row h
    float vbq = bq[h], vb1 = b1[h], vbk = bk[h];
    float4 w[4];
    float a0, a1, a2, a3;

    // ---- Wq ----
    {
        const float4* Wp = (const float4*)(Wq + (size_t)h * HH) + kq * 4;
#pragma unroll
        for (int i = 0; i < 4; i++) w[i] = Wp[i];
        a0 = red8(dot16(w, &zrow[0][kq * 16]));
        a1 = red8(dot16(w, &zrow[1][kq * 16]));
        a2 = red8(dot16(w, &zrow[2][kq * 16]));
        a3 = red8(dot16(w, &zrow[3][kq * 16]));
        if (kq == 0) {
            float* qp = qP + (size_t)bid * 512 + h * 4;
            qp[0] = a0 + vbq; qp[1] = a1 + vbq; qp[2] = a2 + vbq; qp[3] = a3 + vbq;
        }
    }
    // ---- W1i ----
    {
        const float4* Wp = (const float4*)(W1 + (size_t)h * 2 * HH) + kq * 4;
#pragma unroll
        for (int i = 0; i < 4; i++) w[i] = Wp[i];
        a0 = red8(dot16(w, &zrow[0][kq * 16]));
        a1 = red8(dot16(w, &zrow[1][kq * 16]));
        a2 = red8(dot16(w, &zrow[2][kq * 16]));
        a3 = red8(dot16(w, &zrow[3][kq * 16]));
        if (kq == 0) {
            float* cp = cP + (size_t)bid * 512 + h * 4;
            cp[0] = vexp2(KL * (a0 + vb1)); cp[1] = vexp2(KL * (a1 + vb1));
            cp[2] = vexp2(KL * (a2 + vb1)); cp[3] = vexp2(KL * (a3 + vb1));
        }
    }
    // ---- W1j ----
    {
        const float4* Wp = (const float4*)(W1 + (size_t)h * 2 * HH + HH) + kq * 4;
#pragma unroll
        for (int i = 0; i < 4; i++) w[i] = Wp[i];
        a0 = red8(dot16(w, &zrow[0][kq * 16]));
        a1 = red8(dot16(w, &zrow[1][kq * 16]));
        a2 = red8(dot16(w, &zrow[2][kq * 16]));
        a3 = red8(dot16(w, &zrow[3][kq * 16]));
        if (kq == 0) {
            EzjG[(size_t)(r0 + 0) * HH + h] = vexp2(KL * a0);
            EzjG[(size_t)(r0 + 1) * HH + h] = vexp2(KL * a1);
            EzjG[(size_t)(r0 + 2) * HH + h] = vexp2(KL * a2);
            EzjG[(size_t)(r0 + 3) * HH + h] = vexp2(KL * a3);
        }
    }
    // ---- Wk (128x32): 4 o-values per lane ----
    {
        float4 wk = ((const float4*)(Wk + (size_t)h * OO))[kq];
        float4 s0 = *(const float4*)&srow[0][kq * 4];
        float4 s1 = *(const float4*)&srow[1][kq * 4];
        float4 s2 = *(const float4*)&srow[2][kq * 4];
        float4 s3 = *(const float4*)&srow[3][kq * 4];
        a0 = red8(s0.x * wk.x + s0.y * wk.y + s0.z * wk.z + s0.w * wk.w);
        a1 = red8(s1.x * wk.x + s1.y * wk.y + s1.z * wk.z + s1.w * wk.w);
        a2 = red8(s2.x * wk.x + s2.y * wk.y + s2.z * wk.z + s2.w * wk.w);
        a3 = red8(s3.x * wk.x + s3.y * wk.y + s3.z * wk.z + s3.w * wk.w);
        if (kq == 0) {
            int b = r0 >> 9, j0 = r0 & 511;
            float* kp = kTG + ((size_t)b * HH + h) * NN + j0;
            kp[0] = a0 + vbk; kp[1] = a1 + vbk; kp[2] = a2 + vbk; kp[3] = a3 + vbk;
        }
    }
}

// ---------------------------------------------------------------------------
// K2: fused — 256 blocks x 1024 thr, 4 attention rows per block (1/CU).
//   A: load q/Ezi packed [h][4] (coalesced)
//   B: scores, kT read once (h-split)
//   C: masked softmax (2 rows per thread-half)
//   D: acc += attn * rcp(fma(Ezi,Ezj,1)); U = 1-2*acc   [8 rcp chains/iter]
//   E: tail GEMVs from original W2/W3/W4 layout (8-lane split + shuffle reduce)
// LDS: scp(16KB in B/C) and part(32KB in D) share one 32KB buffer.
// ---------------------------------------------------------------------------
__global__ __launch_bounds__(1024, 4) void fused_kernel(
    const float* __restrict__ qP, const float* __restrict__ kTG,
    const float* __restrict__ cP, const float* __restrict__ EzjG,
    const float* __restrict__ W2, const float* __restrict__ b2,
    const float* __restrict__ W3, const float* __restrict__ b3,
    const float* __restrict__ W4, const float* __restrict__ b4,
    float* __restrict__ out) {
    __shared__ float q4T[HH][4];         // 2KB  q packed [h][r]
    __shared__ float c4T[HH][4];         // 2KB  Ezi packed [h][r]
    __shared__ float attnT[NN][4];       // 8KB  attn packed [j][r]
    __shared__ float buf[8192];          // 32KB: scp[2][4][NN] in B/C; part[16][4][HH] in D
    __shared__ float UL[4][HH];          // 2KB
    __shared__ float aggL[4][HH];        // 2KB
    __shared__ float h1L[4][HH];         // 2KB
    __shared__ float redA[16], redB[16];

    float (*scp)[4][NN] = (float (*)[4][NN])buf;
    float (*part)[4][HH] = (float (*)[4][HH])buf;

    int t = threadIdx.x;
    int bid = blockIdx.x;
    int b = bid >> 7;
    int i0 = (bid & 127) * 4;
    int r0 = bid * 4;                    // global row base

    // ---- A: coalesced packed loads ----
    if (t < 512)       ((float*)q4T)[t] = qP[(size_t)bid * 512 + t];
    else               ((float*)c4T)[t - 512] = cP[(size_t)bid * 512 + (t - 512)];
    __syncthreads();

    // ---- B: scores, h-split ----
    {
        int j = t & 511, hs = t >> 9, h0 = hs * 64;
        const float* kb = kTG + ((size_t)b * HH + h0) * NN + j;
        float s0 = 0, s1 = 0, s2 = 0, s3 = 0;
#pragma unroll 8
        for (int hh = 0; hh < 64; hh++) {
            float kv = kb[(size_t)hh * NN];
            float4 qv = *(const float4*)q4T[h0 + hh];   // broadcast
            s0 = fmaf(qv.x, kv, s0); s1 = fmaf(qv.y, kv, s1);
            s2 = fmaf(qv.z, kv, s2); s3 = fmaf(qv.w, kv, s3);
        }
        scp[hs][0][j] = s0; scp[hs][1][j] = s1;
        scp[hs][2][j] = s2; scp[hs][3][j] = s3;
    }
    __syncthreads();

    // ---- C: masked softmax (2 rows per thread-half) ----
    {
        int rp = t >> 9, j = t & 511;
        int lr0 = rp * 2, lr1 = lr0 + 1;
        const float sc = 0.08838834764831845f;  // 1/sqrt(128)
        float s0 = (scp[0][lr0][j] + scp[1][lr0][j]) * sc;
        float s1 = (scp[0][lr1][j] + scp[1][lr1][j]) * sc;
        if (j == i0 + lr0) s0 = -1e30f;
        if (j == i0 + lr1) s1 = -1e30f;
        int lane = t & 63, w = t >> 6, wb = rp * 8;
        float m0 = waveRedMax(s0), m1 = waveRedMax(s1);
        if (lane == 0) { redA[w] = m0; redB[w] = m1; }
        __syncthreads();
        float mm0 = redA[wb], mm1 = redB[wb];
#pragma unroll
        for (int k = 1; k < 8; k++) { mm0 = fmaxf(mm0, redA[wb + k]); mm1 = fmaxf(mm1, redB[wb + k]); }
        float e0 = __expf(s0 - mm0), e1 = __expf(s1 - mm1);
        float p0 = waveRedSum(e0), p1 = waveRedSum(e1);
        __syncthreads();
        if (lane == 0) { redA[w] = p0; redB[w] = p1; }
        __syncthreads();
        float S0 = redA[wb], S1 = redB[wb];
#pragma unroll
        for (int k = 1; k < 8; k++) { S0 += redA[wb + k]; S1 += redB[wb + k]; }
        attnT[j][lr0] = e0 * __fdividef(1.0f, S0);
        attnT[j][lr1] = e1 * __fdividef(1.0f, S1);
    }
    __syncthreads();

    // ---- D: rcp core. thread = (j-slice, h-pair); 8 independent chains ----
    {
        int lane6 = t & 63, qs = t >> 6;     // 16 slices x 32 j
        int hp = lane6 * 2;
        float4 cA = *(const float4*)c4T[hp];       // Ezi rows 0..3 at h=hp
        float4 cB = *(const float4*)c4T[hp + 1];   // at h=hp+1
        const float2* zb2 = (const float2*)(EzjG + (size_t)b * NN * HH) + lane6;
        float a0A = 0, a1A = 0, a2A = 0, a3A = 0;
        float a0B = 0, a1B = 0, a2B = 0, a3B = 0;
        int jb = qs * 32;
#pragma unroll 8
        for (int jj = 0; jj < 32; jj++) {
            int j = jb + jj;
            float2 E = zb2[(size_t)j * 64];
            float4 w = *(const float4*)attnT[j];   // broadcast
            a0A = fmaf(w.x, vrcp(fmaf(cA.x, E.x, 1.0f)), a0A);
            a1A = fmaf(w.y, vrcp(fmaf(cA.y, E.x, 1.0f)), a1A);
            a2A = fmaf(w.z, vrcp(fmaf(cA.z, E.x, 1.0f)), a2A);
            a3A = fmaf(w.w, vrcp(fmaf(cA.w, E.x, 1.0f)), a3A);
            a0B = fmaf(w.x, vrcp(fmaf(cB.x, E.y, 1.0f)), a0B);
            a1B = fmaf(w.y, vrcp(fmaf(cB.y, E.y, 1.0f)), a1B);
            a2B = fmaf(w.z, vrcp(fmaf(cB.z, E.y, 1.0f)), a2B);
            a3B = fmaf(w.w, vrcp(fmaf(cB.w, E.y, 1.0f)), a3B);
        }
        __syncthreads();   // scp reads done (C) before part overwrite
        *(float2*)&part[qs][0][hp] = make_float2(a0A, a0B);
        *(float2*)&part[qs][1][hp] = make_float2(a1A, a1B);
        *(float2*)&part[qs][2][hp] = make_float2(a2A, a2B);
        *(float2*)&part[qs][3][hp] = make_float2(a3A, a3B);
    }
    __syncthreads();
    if (t < 512) {
        int r = t >> 7, h = t & 127;
        float s = 0;
#pragma unroll
        for (int q = 0; q < 16; q++) s += part[q][r][h];
        UL[r][h] = fmaf(-2.0f, s, 1.0f);   // U = 1 - 2*sum (softmax sums to 1)
    }
    __syncthreads();

    // ---- E: tail GEMVs, original weight layout, 8-lane split ----
    {
        int kq = t & 7, h = t >> 3;
        float vb2 = b2[h], vb3 = b3[h], vb4 = b4[h];
        float4 w[4];
        // agg = U@W2.T + b2
        {
            const float4* Wp = (const float4*)(W2 + (size_t)h * HH) + kq * 4;
#pragma unroll
            for (int i = 0; i < 4; i++) w[i] = Wp[i];
            float a0 = red8(dot16(w, &UL[0][kq * 16]));
            float a1 = red8(dot16(w, &UL[1][kq * 16]));
            float a2 = red8(dot16(w, &UL[2][kq * 16]));
            float a3 = red8(dot16(w, &UL[3][kq * 16]));
            if (kq == 0) {
                aggL[0][h] = a0 + vb2; aggL[1][h] = a1 + vb2;
                aggL[2][h] = a2 + vb2; aggL[3][h] = a3 + vb2;
            }
        }
        __syncthreads();
        // h1 = tanh(agg@W3.T + b3)
        {
            const float4* Wp = (const float4*)(W3 + (size_t)h * HH) + kq * 4;
#pragma unroll
            for (int i = 0; i < 4; i++) w[i] = Wp[i];
            float a0 = red8(dot16(w, &aggL[0][kq * 16]));
            float a1 = red8(dot16(w, &aggL[1][kq * 16]));
            float a2 = red8(dot16(w, &aggL[2][kq * 16]));
            float a3 = red8(dot16(w, &aggL[3][kq * 16]));
            if (kq == 0) {
                h1L[0][h] = tanh_fast(a0 + vb3); h1L[1][h] = tanh_fast(a1 + vb3);
                h1L[2][h] = tanh_fast(a2 + vb3); h1L[3][h] = tanh_fast(a3 + vb3);
            }
        }
        __syncthreads();
        // out = h1@W4.T + b4
        {
            const float4* Wp = (const float4*)(W4 + (size_t)h * HH) + kq * 4;
#pragma unroll
            for (int i = 0; i < 4; i++) w[i] = Wp[i];
            float a0 = red8(dot16(w, &h1L[0][kq * 16]));
            float a1 = red8(dot16(w, &h1L[1][kq * 16]));
            float a2 = red8(dot16(w, &h1L[2][kq * 16]));
            float a3 = red8(dot16(w, &h1L[3][kq * 16]));
            if (kq == 0) {
                out[(size_t)(r0 + 0) * HH + h] = a0 + vb4;
                out[(size_t)(r0 + 1) * HH + h] = a1 + vb4;
                out[(size_t)(r0 + 2) * HH + h] = a2 + vb4;
                out[(size_t)(r0 + 3) * HH + h] = a3 + vb4;
            }
        }
    }
}

extern "C" void kernel_launch(void* const* d_in, const int* in_sizes, int n_in,
                              void* d_out, int out_size, void* d_ws, size_t ws_size,
                              hipStream_t stream) {
    const float* z   = (const float*)d_in[0];
    const float* s_t = (const float*)d_in[1];
    const float* W1  = (const float*)d_in[2];
    const float* b1  = (const float*)d_in[3];
    const float* W2  = (const float*)d_in[4];
    const float* b2  = (const float*)d_in[5];
    const float* Wq  = (const float*)d_in[6];
    const float* bq  = (const float*)d_in[7];
    const float* Wk  = (const float*)d_in[8];
    const float* bk  = (const float*)d_in[9];
    const float* W3  = (const float*)d_in[10];
    const float* b3  = (const float*)d_in[11];
    const float* W4  = (const float*)d_in[12];
    const float* b4  = (const float*)d_in[13];
    float* out = (float*)d_out;

    float* ws  = (float*)d_ws;
    float* qP  = ws;                 // 131072  packed [rowgroup][h][4]
    float* kT  = ws + 131072;        // 131072  [b][h][j]
    float* cP  = ws + 262144;        // 131072  packed Ezi [rowgroup][h][4]
    float* Ezj = ws + 393216;        // 131072  [gr][h]

    hipLaunchKernelGGL(prep_kernel, dim3(256), dim3(1024), 0, stream,
                       z, s_t, W1, b1, Wq, bq, Wk, bk, qP, cP, Ezj, kT);
    hipLaunchKernelGGL(fused_kernel, dim3(256), dim3(1024), 0, stream,
                       qP, kT, cP, Ezj, W2, b2, W3, b3, W4, b4, out);
}